// Round 1
// baseline (1634.206 us; speedup 1.0000x reference)
//
#include <hip/hip_runtime.h>
#include <math.h>

#define DM 1024   // d_model
#define NH 16     // heads
#define HD 64     // head dim
#define BB 2      // batch
#define SS 2048   // seq
#define MM (BB*SS)

// ---------------------------------------------------------------------------
// fp32 GEMM: C[M x 1024] = A[M x 1024] @ W[1024 x 1024]
// 128x128 tile, BK=16, 256 threads, 8x8 per thread.
// head_major==1: write C to head-major layout [B, H, S, 64] (for Q/K/V).
// ---------------------------------------------------------------------------
__global__ __launch_bounds__(256) void gemm_f32(const float* __restrict__ A,
                                                const float* __restrict__ W,
                                                float* __restrict__ C,
                                                const int head_major)
{
    __shared__ float As[16][128];   // As[k][m]  (A tile transposed)
    __shared__ float Bs[16][128];   // Bs[k][n]
    const int t  = threadIdx.x;
    const int tx = t & 15;          // n sub-block
    const int ty = t >> 4;          // m sub-block
    const int m0 = blockIdx.y * 128;
    const int n0 = blockIdx.x * 128;

    float acc[8][8];
#pragma unroll
    for (int i = 0; i < 8; ++i)
#pragma unroll
        for (int j = 0; j < 8; ++j) acc[i][j] = 0.f;

    const int arow = t >> 2;         // 0..63
    const int ak4  = (t & 3) << 2;   // 0,4,8,12
    const int brow = t >> 4;         // 0..15
    const int bcol = (t & 15) << 3;  // 0..120

    for (int k0 = 0; k0 < DM; k0 += 16) {
#pragma unroll
        for (int p = 0; p < 2; ++p) {
            const int row = arow + p * 64;
            const float4 v = *(const float4*)(A + (size_t)(m0 + row) * DM + k0 + ak4);
            As[ak4 + 0][row] = v.x;
            As[ak4 + 1][row] = v.y;
            As[ak4 + 2][row] = v.z;
            As[ak4 + 3][row] = v.w;
        }
        {
            const float4 v0 = *(const float4*)(W + (size_t)(k0 + brow) * DM + n0 + bcol);
            const float4 v1 = *(const float4*)(W + (size_t)(k0 + brow) * DM + n0 + bcol + 4);
            *(float4*)&Bs[brow][bcol]     = v0;
            *(float4*)&Bs[brow][bcol + 4] = v1;
        }
        __syncthreads();
#pragma unroll
        for (int k = 0; k < 16; ++k) {
            float a[8], b[8];
            *(float4*)&a[0] = *(const float4*)&As[k][ty * 8];
            *(float4*)&a[4] = *(const float4*)&As[k][ty * 8 + 4];
            *(float4*)&b[0] = *(const float4*)&Bs[k][tx * 8];
            *(float4*)&b[4] = *(const float4*)&Bs[k][tx * 8 + 4];
#pragma unroll
            for (int i = 0; i < 8; ++i)
#pragma unroll
                for (int j = 0; j < 8; ++j)
                    acc[i][j] = fmaf(a[i], b[j], acc[i][j]);
        }
        __syncthreads();
    }

    if (head_major == 0) {
#pragma unroll
        for (int i = 0; i < 8; ++i) {
            float* dst = C + (size_t)(m0 + ty * 8 + i) * DM + n0 + tx * 8;
            *(float4*)dst       = *(float4*)&acc[i][0];
            *(float4*)(dst + 4) = *(float4*)&acc[i][4];
        }
    } else {
        // (m, n) -> [b, h, s, d] with m = b*S + s, n = h*64 + d
#pragma unroll
        for (int i = 0; i < 8; ++i) {
            const int m = m0 + ty * 8 + i;
            const int n = n0 + tx * 8;
            const int b = m >> 11, s = m & (SS - 1);
            const int h = n >> 6,  d = n & (HD - 1);
            float* dst = C + ((size_t)((b << 4) + h) * SS + s) * HD + d;
            *(float4*)dst       = *(float4*)&acc[i][0];
            *(float4*)(dst + 4) = *(float4*)&acc[i][4];
        }
    }
}

// ---------------------------------------------------------------------------
// RoPE in-place on head-major Q and K. One thread per (tensor, b, h, s, j<32).
// Folds the attention scale 1/sqrt(D_MODEL) = 1/32 into Q.
// ---------------------------------------------------------------------------
__global__ __launch_bounds__(256) void rope_f32(float* __restrict__ Qh, float* __restrict__ Kh)
{
    const int idx   = blockIdx.x * 256 + threadIdx.x;  // 0 .. 2*BH*S*32-1 = 4194303
    const int which = idx >> 21;                       // 0 = Q, 1 = K
    const int rem   = idx & ((1 << 21) - 1);
    const int j     = rem & 31;                        // pair index 0..31
    const int bhs   = rem >> 5;                        // (b*H + h)*S + s
    const int s     = bhs & (SS - 1);

    float* p = (which ? Kh : Qh) + (size_t)bhs * HD;
    const float v1 = p[j];
    const float v2 = p[j + 32];
    const float inv_freq = powf(10000.f, -(float)j * (1.f / 32.f));
    const float f = (float)s * inv_freq;
    float sn, cs;
    sincosf(f, &sn, &cs);   // accurate range reduction: scores are tie-sensitive
    const float sc = which ? 1.f : (1.f / 32.f);
    p[j]      = (v1 * cs - v2 * sn) * sc;
    p[j + 32] = (v1 * sn + v2 * cs) * sc;
}

// ---------------------------------------------------------------------------
// Flash-style fp32 attention. Block = 256 threads = 64 q-rows x 4 lanes/row.
// Grid = (S/64 q-tiles, B*H). Q row cached in registers; K/V/P tiles in LDS.
// Writes merged[M x 1024] (layout [b, s, h, d]).
// ---------------------------------------------------------------------------
__global__ __launch_bounds__(256) void attn_f32(const float* __restrict__ Qh,
                                                const float* __restrict__ Kh,
                                                const float* __restrict__ Vh,
                                                float* __restrict__ Mg)
{
    __shared__ float Ks[64][68];
    __shared__ float Vs[64][68];
    __shared__ float Ps[64][68];

    const int t  = threadIdx.x;
    const int r  = t >> 2;   // q row within tile
    const int q  = t & 3;    // quarter (owns cols 4i+q of scores, dims q*16.. of O)
    const int bh = blockIdx.y;
    const int q0 = blockIdx.x * 64;

    const float* Qb = Qh + (size_t)bh * SS * HD;
    const float* Kb = Kh + (size_t)bh * SS * HD;
    const float* Vb = Vh + (size_t)bh * SS * HD;

    // cache my q row (pre-scaled by 1/32 in rope_f32)
    float qreg[64];
#pragma unroll
    for (int i = 0; i < 16; ++i) {
        const float4 v = *(const float4*)(Qb + (size_t)(q0 + r) * HD + i * 4);
        qreg[4 * i + 0] = v.x; qreg[4 * i + 1] = v.y;
        qreg[4 * i + 2] = v.z; qreg[4 * i + 3] = v.w;
    }

    float O[16];
#pragma unroll
    for (int i = 0; i < 16; ++i) O[i] = 0.f;
    float mrow = -1e30f, lrow = 0.f;

    const int lr = t >> 2;          // staging row
    const int lc = (t & 3) * 16;    // staging col base (lane t reads bytes 64t..: coalesced)

    for (int k0 = 0; k0 < SS; k0 += 64) {
        __syncthreads();  // prior PV done with Ks/Vs/Ps
#pragma unroll
        for (int i = 0; i < 4; ++i) {
            *(float4*)&Ks[lr][lc + 4 * i] = *(const float4*)(Kb + (size_t)(k0 + lr) * HD + lc + 4 * i);
            *(float4*)&Vs[lr][lc + 4 * i] = *(const float4*)(Vb + (size_t)(k0 + lr) * HD + lc + 4 * i);
        }
        __syncthreads();

        // scores for 16 cols c = 4i+q  (consecutive c across the 4 lanes: no bank conflict)
        float sv[16];
#pragma unroll
        for (int i = 0; i < 16; ++i) {
            const int c = 4 * i + q;
            float dot = 0.f;
#pragma unroll
            for (int d = 0; d < 64; d += 4) {
                const float4 kv = *(const float4*)&Ks[c][d];
                dot = fmaf(qreg[d + 0], kv.x, dot);
                dot = fmaf(qreg[d + 1], kv.y, dot);
                dot = fmaf(qreg[d + 2], kv.z, dot);
                dot = fmaf(qreg[d + 3], kv.w, dot);
            }
            sv[i] = dot;
        }

        // online softmax (row state replicated across the 4 lanes of a row)
        float mloc = sv[0];
#pragma unroll
        for (int i = 1; i < 16; ++i) mloc = fmaxf(mloc, sv[i]);
        mloc = fmaxf(mloc, __shfl_xor(mloc, 1));
        mloc = fmaxf(mloc, __shfl_xor(mloc, 2));
        const float mnew  = fmaxf(mrow, mloc);
        const float alpha = __expf(mrow - mnew);
        float psum = 0.f;
#pragma unroll
        for (int i = 0; i < 16; ++i) {
            const float p = __expf(sv[i] - mnew);
            Ps[r][4 * i + q] = p;
            psum += p;
        }
        psum += __shfl_xor(psum, 1);
        psum += __shfl_xor(psum, 2);
        lrow = lrow * alpha + psum;
        mrow = mnew;
#pragma unroll
        for (int i = 0; i < 16; ++i) O[i] *= alpha;
        __syncthreads();  // Ps visible to all lanes of the row group

        // O[dd] += sum_c P[r][c] * V[c][q*16+dd]
#pragma unroll
        for (int c = 0; c < 64; ++c) {
            const float p = Ps[r][c];
#pragma unroll
            for (int dd = 0; dd < 16; dd += 4) {
                const float4 vv = *(const float4*)&Vs[c][q * 16 + dd];
                O[dd + 0] = fmaf(p, vv.x, O[dd + 0]);
                O[dd + 1] = fmaf(p, vv.y, O[dd + 1]);
                O[dd + 2] = fmaf(p, vv.z, O[dd + 2]);
                O[dd + 3] = fmaf(p, vv.w, O[dd + 3]);
            }
        }
    }

    // epilogue: merged[b, s, h, d]
    const float inv = 1.f / lrow;
    const int b = bh >> 4, h = bh & 15;
    float* dst = Mg + (size_t)((b * SS) + q0 + r) * DM + h * HD + q * 16;
#pragma unroll
    for (int dd = 0; dd < 16; dd += 4) {
        float4 o;
        o.x = O[dd + 0] * inv; o.y = O[dd + 1] * inv;
        o.z = O[dd + 2] * inv; o.w = O[dd + 3] * inv;
        *(float4*)(dst + dd) = o;
    }
}

// ---------------------------------------------------------------------------
extern "C" void kernel_launch(void* const* d_in, const int* in_sizes, int n_in,
                              void* d_out, int out_size, void* d_ws, size_t ws_size,
                              hipStream_t stream)
{
    const float* x  = (const float*)d_in[0];
    const float* qw = (const float*)d_in[1];
    const float* kw = (const float*)d_in[2];
    const float* vw = (const float*)d_in[3];
    const float* ow = (const float*)d_in[4];
    float* out = (float*)d_out;

    // workspace: Qh | Kh | Vh | merged  (4 x 16 MB = 64 MB)
    float* Qh = (float*)d_ws;
    float* Kh = Qh + (size_t)MM * DM;
    float* Vh = Kh + (size_t)MM * DM;
    float* Mg = Vh + (size_t)MM * DM;

    const dim3 gg(DM / 128, MM / 128);  // (8, 32)
    gemm_f32<<<gg, 256, 0, stream>>>(x, qw, Qh, 1);
    gemm_f32<<<gg, 256, 0, stream>>>(x, kw, Kh, 1);
    gemm_f32<<<gg, 256, 0, stream>>>(x, vw, Vh, 1);

    rope_f32<<<(2 * BB * NH * SS * 32) / 256, 256, 0, stream>>>(Qh, Kh);

    attn_f32<<<dim3(SS / 64, BB * NH), 256, 0, stream>>>(Qh, Kh, Vh, Mg);

    gemm_f32<<<gg, 256, 0, stream>>>(Mg, ow, out, 0);
}

// Round 2
// 827.507 us; speedup vs baseline: 1.9749x; 1.9749x over previous
//
#include <hip/hip_runtime.h>
#include <math.h>

#define DM 1024   // d_model
#define NH 16     // heads
#define HD 64     // head dim
#define BB 2      // batch
#define SS 2048   // seq
#define MM (BB*SS)

typedef __attribute__((ext_vector_type(8))) short short8;    // 8 bf16 = one MFMA A/B fragment
typedef __attribute__((ext_vector_type(4))) float floatx4;   // MFMA C/D fragment

// bf16 helpers (RNE)
__device__ __forceinline__ unsigned short f2bf(float f) {
    unsigned int u = __float_as_uint(f);
    unsigned int r = u + 0x7fffu + ((u >> 16) & 1u);
    return (unsigned short)(r >> 16);
}
__device__ __forceinline__ float bf2f(unsigned short h) {
    return __uint_as_float(((unsigned int)h) << 16);
}

// ---------------------------------------------------------------------------
// fp32 GEMM (unchanged from round 1): C[M x 1024] = A[M x 1024] @ W[1024 x 1024]
// head_major==1: write C to [B, H, S, 64].
// ---------------------------------------------------------------------------
__global__ __launch_bounds__(256) void gemm_f32(const float* __restrict__ A,
                                                const float* __restrict__ W,
                                                float* __restrict__ C,
                                                const int head_major)
{
    __shared__ float As[16][128];
    __shared__ float Bs[16][128];
    const int t  = threadIdx.x;
    const int tx = t & 15;
    const int ty = t >> 4;
    const int m0 = blockIdx.y * 128;
    const int n0 = blockIdx.x * 128;

    float acc[8][8];
#pragma unroll
    for (int i = 0; i < 8; ++i)
#pragma unroll
        for (int j = 0; j < 8; ++j) acc[i][j] = 0.f;

    const int arow = t >> 2;
    const int ak4  = (t & 3) << 2;
    const int brow = t >> 4;
    const int bcol = (t & 15) << 3;

    for (int k0 = 0; k0 < DM; k0 += 16) {
#pragma unroll
        for (int p = 0; p < 2; ++p) {
            const int row = arow + p * 64;
            const float4 v = *(const float4*)(A + (size_t)(m0 + row) * DM + k0 + ak4);
            As[ak4 + 0][row] = v.x;
            As[ak4 + 1][row] = v.y;
            As[ak4 + 2][row] = v.z;
            As[ak4 + 3][row] = v.w;
        }
        {
            const float4 v0 = *(const float4*)(W + (size_t)(k0 + brow) * DM + n0 + bcol);
            const float4 v1 = *(const float4*)(W + (size_t)(k0 + brow) * DM + n0 + bcol + 4);
            *(float4*)&Bs[brow][bcol]     = v0;
            *(float4*)&Bs[brow][bcol + 4] = v1;
        }
        __syncthreads();
#pragma unroll
        for (int k = 0; k < 16; ++k) {
            float a[8], b[8];
            *(float4*)&a[0] = *(const float4*)&As[k][ty * 8];
            *(float4*)&a[4] = *(const float4*)&As[k][ty * 8 + 4];
            *(float4*)&b[0] = *(const float4*)&Bs[k][tx * 8];
            *(float4*)&b[4] = *(const float4*)&Bs[k][tx * 8 + 4];
#pragma unroll
            for (int i = 0; i < 8; ++i)
#pragma unroll
                for (int j = 0; j < 8; ++j)
                    acc[i][j] = fmaf(a[i], b[j], acc[i][j]);
        }
        __syncthreads();
    }

    if (head_major == 0) {
#pragma unroll
        for (int i = 0; i < 8; ++i) {
            float* dst = C + (size_t)(m0 + ty * 8 + i) * DM + n0 + tx * 8;
            *(float4*)dst       = *(float4*)&acc[i][0];
            *(float4*)(dst + 4) = *(float4*)&acc[i][4];
        }
    } else {
#pragma unroll
        for (int i = 0; i < 8; ++i) {
            const int m = m0 + ty * 8 + i;
            const int n = n0 + tx * 8;
            const int b = m >> 11, s = m & (SS - 1);
            const int h = n >> 6,  d = n & (HD - 1);
            float* dst = C + ((size_t)((b << 4) + h) * SS + s) * HD + d;
            *(float4*)dst       = *(float4*)&acc[i][0];
            *(float4*)(dst + 4) = *(float4*)&acc[i][4];
        }
    }
}

// ---------------------------------------------------------------------------
// RoPE in-place on head-major Q and K (unchanged). Folds 1/32 score scale into Q.
// ---------------------------------------------------------------------------
__global__ __launch_bounds__(256) void rope_f32(float* __restrict__ Qh, float* __restrict__ Kh)
{
    const int idx   = blockIdx.x * 256 + threadIdx.x;
    const int which = idx >> 21;
    const int rem   = idx & ((1 << 21) - 1);
    const int j     = rem & 31;
    const int bhs   = rem >> 5;
    const int s     = bhs & (SS - 1);

    float* p = (which ? Kh : Qh) + (size_t)bhs * HD;
    const float v1 = p[j];
    const float v2 = p[j + 32];
    const float inv_freq = powf(10000.f, -(float)j * (1.f / 32.f));
    const float f = (float)s * inv_freq;
    float sn, cs;
    sincosf(f, &sn, &cs);
    const float sc = which ? 1.f : (1.f / 32.f);
    p[j]      = (v1 * cs - v2 * sn) * sc;
    p[j + 32] = (v1 * sn + v2 * cs) * sc;
}

// ---------------------------------------------------------------------------
// MFMA flash attention.
// Block = 256 threads = 4 waves; Q-tile = 128 rows (32/wave); K-tile = 64.
// Split-bf16 QK^T (hi+lo: S = Qhi.Khi + Qlo.Khi + Qhi.Klo -> fp32-grade scores,
// needed because scores ~ N(0,256) make softmax argmax-sharp). Plain bf16 PV.
// Fragment layouts (guide §3, m89/m91-verified):
//   A[m][k]: m=lane&15, k=quad*8+j ; B[k][n]: n=lane&15, k=quad*8+j
//   C/D:     col=lane&15, row=quad*4+reg
// LDS stride 72 ushorts: 16B-aligned rows, 4-bank rotation per row so the
// 16-row x 4-quad fragment reads tile all 32 banks per 8-lane group.
// ---------------------------------------------------------------------------
#define PSTR 72

__global__ __launch_bounds__(256, 2) void attn_mfma(const float* __restrict__ Qh,
                                                    const float* __restrict__ Kh,
                                                    const float* __restrict__ Vh,
                                                    float* __restrict__ Mg)
{
    __shared__ unsigned short KhiS[64 * PSTR];
    __shared__ unsigned short KloS[64 * PSTR];
    __shared__ unsigned short VtS [64 * PSTR];   // V transposed: [dim][key]
    __shared__ unsigned short PS  [128 * PSTR];  // P: [qrow-in-block][key] (wave-local rows)

    const int t    = threadIdx.x;
    const int w    = t >> 6;
    const int lane = t & 63;
    const int col  = lane & 15;
    const int quad = lane >> 4;

    const int bh = blockIdx.y;
    const int q0 = blockIdx.x * 128;
    const float* Qb = Qh + (size_t)bh * SS * HD;
    const float* Kb = Kh + (size_t)bh * SS * HD;
    const float* Vb = Vh + (size_t)bh * SS * HD;

    // --- Q fragments from global, split hi/lo, cached for the whole K-loop ---
    short8 qhi[2][2], qlo[2][2];   // [mi][chunk]
#pragma unroll
    for (int mi = 0; mi < 2; ++mi) {
#pragma unroll
        for (int ch = 0; ch < 2; ++ch) {
            const float* p = Qb + (size_t)(q0 + w * 32 + mi * 16 + col) * HD + ch * 32 + quad * 8;
            const float4 a = *(const float4*)p;
            const float4 b = *(const float4*)(p + 4);
            float v[8] = {a.x, a.y, a.z, a.w, b.x, b.y, b.z, b.w};
#pragma unroll
            for (int j = 0; j < 8; ++j) {
                const unsigned short h = f2bf(v[j]);
                qhi[mi][ch][j] = (short)h;
                qlo[mi][ch][j] = (short)f2bf(v[j] - bf2f(h));
            }
        }
    }

    floatx4 Oacc[2][4];   // [mi][ntile(dim)]
#pragma unroll
    for (int mi = 0; mi < 2; ++mi)
#pragma unroll
        for (int nt = 0; nt < 4; ++nt) Oacc[mi][nt] = (floatx4){0.f, 0.f, 0.f, 0.f};
    float mrow[2][4], lrow[2][4];
#pragma unroll
    for (int mi = 0; mi < 2; ++mi)
#pragma unroll
        for (int r = 0; r < 4; ++r) { mrow[mi][r] = -1e30f; lrow[mi][r] = 0.f; }

    const int skey = t >> 2;          // staging: key row
    const int sd0  = (t & 3) * 16;    // staging: 16-dim group

    for (int k0 = 0; k0 < SS; k0 += 64) {
        __syncthreads();   // all waves done reading prev K/V tiles

        // --- stage K (hi/lo) and V^T as bf16 ---
        {
            const float* kp = Kb + (size_t)(k0 + skey) * HD + sd0;
            const float* vp = Vb + (size_t)(k0 + skey) * HD + sd0;
            float kv[16], vv[16];
#pragma unroll
            for (int i = 0; i < 4; ++i) {
                *(float4*)&kv[4 * i] = *(const float4*)(kp + 4 * i);
                *(float4*)&vv[4 * i] = *(const float4*)(vp + 4 * i);
            }
            short8 h0, h1, l0, l1;
#pragma unroll
            for (int i = 0; i < 16; ++i) {
                const unsigned short h = f2bf(kv[i]);
                const unsigned short l = f2bf(kv[i] - bf2f(h));
                if (i < 8) { h0[i] = (short)h; l0[i] = (short)l; }
                else       { h1[i - 8] = (short)h; l1[i - 8] = (short)l; }
            }
            *(short8*)&KhiS[skey * PSTR + sd0]     = h0;
            *(short8*)&KhiS[skey * PSTR + sd0 + 8] = h1;
            *(short8*)&KloS[skey * PSTR + sd0]     = l0;
            *(short8*)&KloS[skey * PSTR + sd0 + 8] = l1;
#pragma unroll
            for (int i = 0; i < 16; ++i)
                VtS[(sd0 + i) * PSTR + skey] = f2bf(vv[i]);
        }
        __syncthreads();

        // --- scores: S = Qhi.Khi + Qlo.Khi + Qhi.Klo (extended-K split-bf16) ---
        floatx4 sc[2][4];
#pragma unroll
        for (int nt = 0; nt < 4; ++nt) {
            short8 kh[2], kl[2];
#pragma unroll
            for (int ch = 0; ch < 2; ++ch) {
                kh[ch] = *(const short8*)&KhiS[(nt * 16 + col) * PSTR + ch * 32 + quad * 8];
                kl[ch] = *(const short8*)&KloS[(nt * 16 + col) * PSTR + ch * 32 + quad * 8];
            }
#pragma unroll
            for (int mi = 0; mi < 2; ++mi) {
                floatx4 a = (floatx4){0.f, 0.f, 0.f, 0.f};
#pragma unroll
                for (int ch = 0; ch < 2; ++ch)
                    a = __builtin_amdgcn_mfma_f32_16x16x32_bf16(qhi[mi][ch], kh[ch], a, 0, 0, 0);
#pragma unroll
                for (int ch = 0; ch < 2; ++ch)
                    a = __builtin_amdgcn_mfma_f32_16x16x32_bf16(qlo[mi][ch], kh[ch], a, 0, 0, 0);
#pragma unroll
                for (int ch = 0; ch < 2; ++ch)
                    a = __builtin_amdgcn_mfma_f32_16x16x32_bf16(qhi[mi][ch], kl[ch], a, 0, 0, 0);
                sc[mi][nt] = a;
            }
        }

        // --- online softmax (row = quad*4+reg; cols spread over 16 lanes of quad) ---
#pragma unroll
        for (int mi = 0; mi < 2; ++mi) {
            float mx[4], al[4], ps[4];
#pragma unroll
            for (int r = 0; r < 4; ++r) {
                float m = sc[mi][0][r];
#pragma unroll
                for (int nt = 1; nt < 4; ++nt) m = fmaxf(m, sc[mi][nt][r]);
                m = fmaxf(m, __shfl_xor(m, 1));
                m = fmaxf(m, __shfl_xor(m, 2));
                m = fmaxf(m, __shfl_xor(m, 4));
                m = fmaxf(m, __shfl_xor(m, 8));
                mx[r] = m;
            }
#pragma unroll
            for (int r = 0; r < 4; ++r) {
                const float mnew = fmaxf(mrow[mi][r], mx[r]);
                al[r] = __expf(mrow[mi][r] - mnew);
                mrow[mi][r] = mnew;
                ps[r] = 0.f;
            }
#pragma unroll
            for (int nt = 0; nt < 4; ++nt)
#pragma unroll
                for (int r = 0; r < 4; ++r) {
                    const float p = __expf(sc[mi][nt][r] - mrow[mi][r]);
                    sc[mi][nt][r] = p;
                    ps[r] += p;
                }
#pragma unroll
            for (int r = 0; r < 4; ++r) {
                ps[r] += __shfl_xor(ps[r], 1);
                ps[r] += __shfl_xor(ps[r], 2);
                ps[r] += __shfl_xor(ps[r], 4);
                ps[r] += __shfl_xor(ps[r], 8);
                lrow[mi][r] = lrow[mi][r] * al[r] + ps[r];
            }
#pragma unroll
            for (int nt = 0; nt < 4; ++nt)
#pragma unroll
                for (int r = 0; r < 4; ++r) Oacc[mi][nt][r] *= al[r];
            // P -> LDS (wave-local rows; C-layout -> A-layout round trip)
#pragma unroll
            for (int nt = 0; nt < 4; ++nt)
#pragma unroll
                for (int r = 0; r < 4; ++r)
                    PS[(w * 32 + mi * 16 + quad * 4 + r) * PSTR + nt * 16 + col] =
                        f2bf(sc[mi][nt][r]);
        }

        // --- PV: O += P @ V ---
#pragma unroll
        for (int nt = 0; nt < 4; ++nt) {
            short8 vf[2];
#pragma unroll
            for (int ch = 0; ch < 2; ++ch)
                vf[ch] = *(const short8*)&VtS[(nt * 16 + col) * PSTR + ch * 32 + quad * 8];
#pragma unroll
            for (int mi = 0; mi < 2; ++mi) {
                short8 pf[2];
#pragma unroll
                for (int ch = 0; ch < 2; ++ch)
                    pf[ch] = *(const short8*)&PS[(w * 32 + mi * 16 + col) * PSTR + ch * 32 + quad * 8];
#pragma unroll
                for (int ch = 0; ch < 2; ++ch)
                    Oacc[mi][nt] = __builtin_amdgcn_mfma_f32_16x16x32_bf16(pf[ch], vf[ch], Oacc[mi][nt], 0, 0, 0);
            }
        }
    }

    // --- epilogue: merged[b, s, h*64 + dim] ---
    const int b = bh >> 4, h = bh & 15;
#pragma unroll
    for (int mi = 0; mi < 2; ++mi) {
        float inv[4];
#pragma unroll
        for (int r = 0; r < 4; ++r) inv[r] = 1.f / lrow[mi][r];
#pragma unroll
        for (int nt = 0; nt < 4; ++nt)
#pragma unroll
            for (int r = 0; r < 4; ++r) {
                const int srow = q0 + w * 32 + mi * 16 + quad * 4 + r;
                Mg[(size_t)(b * SS + srow) * DM + h * HD + nt * 16 + col] = Oacc[mi][nt][r] * inv[r];
            }
    }
}

// ---------------------------------------------------------------------------
extern "C" void kernel_launch(void* const* d_in, const int* in_sizes, int n_in,
                              void* d_out, int out_size, void* d_ws, size_t ws_size,
                              hipStream_t stream)
{
    const float* x  = (const float*)d_in[0];
    const float* qw = (const float*)d_in[1];
    const float* kw = (const float*)d_in[2];
    const float* vw = (const float*)d_in[3];
    const float* ow = (const float*)d_in[4];
    float* out = (float*)d_out;

    float* Qh = (float*)d_ws;
    float* Kh = Qh + (size_t)MM * DM;
    float* Vh = Kh + (size_t)MM * DM;
    float* Mg = Vh + (size_t)MM * DM;

    const dim3 gg(DM / 128, MM / 128);
    gemm_f32<<<gg, 256, 0, stream>>>(x, qw, Qh, 1);
    gemm_f32<<<gg, 256, 0, stream>>>(x, kw, Kh, 1);
    gemm_f32<<<gg, 256, 0, stream>>>(x, vw, Vh, 1);

    rope_f32<<<(2 * BB * NH * SS * 32) / 256, 256, 0, stream>>>(Qh, Kh);

    attn_mfma<<<dim3(SS / 128, BB * NH), 256, 0, stream>>>(Qh, Kh, Vh, Mg);

    gemm_f32<<<gg, 256, 0, stream>>>(Mg, ow, out, 0);
}

// Round 3
// 339.205 us; speedup vs baseline: 4.8178x; 2.4395x over previous
//
#include <hip/hip_runtime.h>
#include <math.h>

#define DM 1024   // d_model
#define NH 16     // heads
#define HD 64     // head dim
#define BB 2      // batch
#define SS 2048   // seq
#define MM (BB*SS)

typedef unsigned short ushort_t;
typedef __attribute__((ext_vector_type(8))) short short8;    // 8 bf16 = MFMA A/B fragment
typedef __attribute__((ext_vector_type(4))) float floatx4;   // MFMA C/D fragment

// bf16 helpers (RNE)
__device__ __forceinline__ ushort_t f2bf(float f) {
    unsigned int u = __float_as_uint(f);
    unsigned int r = u + 0x7fffu + ((u >> 16) & 1u);
    return (ushort_t)(r >> 16);
}
__device__ __forceinline__ float bf2f(ushort_t h) {
    return __uint_as_float(((unsigned int)h) << 16);
}

// async 16B global->LDS (per-lane global addr, wave-uniform LDS base + lane*16)
__device__ __forceinline__ void gl_lds16(const ushort_t* g, ushort_t* l) {
    __builtin_amdgcn_global_load_lds(
        (const __attribute__((address_space(1))) unsigned int*)g,
        (__attribute__((address_space(3))) unsigned int*)l, 16, 0, 0);
}

// ---------------------------------------------------------------------------
// Conversions
// ---------------------------------------------------------------------------
__global__ __launch_bounds__(256) void convert_x(const float* __restrict__ X,
                                                 ushort_t* __restrict__ Xh,
                                                 ushort_t* __restrict__ Xl)
{
    const size_t base = ((size_t)blockIdx.x * 256 + threadIdx.x) * 8;
    float v[8];
    *(float4*)&v[0] = *(const float4*)(X + base);
    *(float4*)&v[4] = *(const float4*)(X + base + 4);
    short8 h, l;
#pragma unroll
    for (int i = 0; i < 8; ++i) {
        const ushort_t hi = f2bf(v[i]);
        h[i] = (short)hi;
        l[i] = (short)f2bf(v[i] - bf2f(hi));
    }
    *(short8*)(Xh + base) = h;
    *(short8*)(Xl + base) = l;
}

// W[k][n] fp32 -> Wt[n][k] bf16 hi (+lo). grid (nb, kb), 64x64 tiles.
template<int SPLIT>
__global__ __launch_bounds__(256) void convert_wt(const float* __restrict__ W,
                                                  ushort_t* __restrict__ Th,
                                                  ushort_t* __restrict__ Tl)
{
    __shared__ float tile[64][65];
    const int t  = threadIdx.x;
    const int kb = blockIdx.y * 64, nb = blockIdx.x * 64;
    const int r  = t >> 2;
    const int c0 = (t & 3) * 16;
#pragma unroll
    for (int i = 0; i < 4; ++i)
        *(float4*)&tile[r][c0 + 4 * i] = *(const float4*)(W + (size_t)(kb + r) * DM + nb + c0 + 4 * i);
    __syncthreads();
    ushort_t hi[16], lo[16];
#pragma unroll
    for (int i = 0; i < 16; ++i) {
        const float v = tile[c0 + i][r];
        hi[i] = f2bf(v);
        if (SPLIT) lo[i] = f2bf(v - bf2f(hi[i]));
    }
    const size_t dst = (size_t)(nb + r) * DM + kb + c0;
    *(short8*)(Th + dst)     = *(short8*)&hi[0];
    *(short8*)(Th + dst + 8) = *(short8*)&hi[8];
    if (SPLIT) {
        *(short8*)(Tl + dst)     = *(short8*)&lo[0];
        *(short8*)(Tl + dst + 8) = *(short8*)&lo[8];
    }
}

// ---------------------------------------------------------------------------
// MFMA GEMM. C[M x N] = A[M x K] @ Bt[N x K]^T, A/B bf16 (optionally split
// hi+lo 3-term), fp32 accumulate. Tile GTM=128 x TN, BK k-step, 4 waves 2x2.
// Staging: global_load_lds width 16 with XOR swizzle on 16B units so both
// the lane-ordered LDS writes and the MFMA fragment ds_read_b128 are
// conflict-free.  OUT_MODE: 0 flat fp32, 1 head-major fp32 (fused Q|K via
// n>>10), 2 head-major bf16.
// ---------------------------------------------------------------------------
#define GTM 128

template<int UPR, int SH>
__device__ __forceinline__ void stage_tile(const ushort_t* __restrict__ G,
                                           ushort_t* L, int rows, int w, int lane)
{
    const int iters = rows * UPR / 256;
#pragma unroll
    for (int i = 0; i < iters; ++i) {
        const int p0 = (i * 4 + w) * 64;
        const int p  = p0 + lane;
        const int r  = p / UPR;
        const int u  = (p % UPR) ^ ((r >> SH) & (UPR - 1));
        gl_lds16(G + (size_t)r * DM + u * 8, L + (size_t)p0 * 8);
    }
}

template<int UPR, int SH>
__device__ __forceinline__ short8 frag(const ushort_t* L, int r, int u)
{
    const int uu = u ^ ((r >> SH) & (UPR - 1));
    return *(const short8*)&L[((size_t)r * UPR + uu) * 8];
}

template<int SPLIT, int OUT_MODE, int TN, int BK>
__global__ __launch_bounds__(256, 2) void gemm_mfma(
    const ushort_t* __restrict__ Ah, const ushort_t* __restrict__ Al,
    const ushort_t* __restrict__ Bh, const ushort_t* __restrict__ Bl,
    float* __restrict__ Cf, ushort_t* __restrict__ Cb)
{
    constexpr int UPR = BK / 8;              // 16B units per LDS row
    constexpr int KC  = BK / 32;             // MFMA k-chunks per step
    constexpr int NI  = TN / 32;             // per-wave n-tiles
    constexpr int SH  = (UPR == 4) ? 1 : 0;  // swizzle shift

    __shared__ __align__(16) ushort_t AsH[GTM * BK];
    __shared__ __align__(16) ushort_t BsH[TN * BK];
    __shared__ __align__(16) ushort_t AsL[SPLIT ? GTM * BK : 8];
    __shared__ __align__(16) ushort_t BsL[SPLIT ? TN * BK : 8];

    const int t    = threadIdx.x;
    const int w    = t >> 6;
    const int lane = t & 63;
    const int col  = lane & 15;
    const int quad = lane >> 4;
    const int wm   = w & 1;
    const int wn   = w >> 1;
    const int m0   = blockIdx.y * GTM;
    const int n0   = blockIdx.x * TN;

    floatx4 acc[4][NI];
#pragma unroll
    for (int mi = 0; mi < 4; ++mi)
#pragma unroll
        for (int ni = 0; ni < NI; ++ni) acc[mi][ni] = (floatx4){0.f, 0.f, 0.f, 0.f};

    for (int k0 = 0; k0 < DM; k0 += BK) {
        __syncthreads();
        stage_tile<UPR, SH>(Ah + (size_t)m0 * DM + k0, AsH, GTM, w, lane);
        if (SPLIT) stage_tile<UPR, SH>(Al + (size_t)m0 * DM + k0, AsL, GTM, w, lane);
        stage_tile<UPR, SH>(Bh + (size_t)n0 * DM + k0, BsH, TN, w, lane);
        if (SPLIT) stage_tile<UPR, SH>(Bl + (size_t)n0 * DM + k0, BsL, TN, w, lane);
        __syncthreads();

#pragma unroll
        for (int kc = 0; kc < KC; ++kc) {
            short8 ah[4], bh[NI];
            short8 al[SPLIT ? 4 : 1], bl[SPLIT ? NI : 1];
#pragma unroll
            for (int mi = 0; mi < 4; ++mi) {
                const int r = wm * 64 + mi * 16 + col;
                ah[mi] = frag<UPR, SH>(AsH, r, kc * 4 + quad);
                if (SPLIT) al[mi] = frag<UPR, SH>(AsL, r, kc * 4 + quad);
            }
#pragma unroll
            for (int ni = 0; ni < NI; ++ni) {
                const int r = wn * (TN / 2) + ni * 16 + col;
                bh[ni] = frag<UPR, SH>(BsH, r, kc * 4 + quad);
                if (SPLIT) bl[ni] = frag<UPR, SH>(BsL, r, kc * 4 + quad);
            }
#pragma unroll
            for (int mi = 0; mi < 4; ++mi)
#pragma unroll
                for (int ni = 0; ni < NI; ++ni) {
                    acc[mi][ni] = __builtin_amdgcn_mfma_f32_16x16x32_bf16(ah[mi], bh[ni], acc[mi][ni], 0, 0, 0);
                    if (SPLIT) {
                        acc[mi][ni] = __builtin_amdgcn_mfma_f32_16x16x32_bf16(al[mi], bh[ni], acc[mi][ni], 0, 0, 0);
                        acc[mi][ni] = __builtin_amdgcn_mfma_f32_16x16x32_bf16(ah[mi], bl[ni], acc[mi][ni], 0, 0, 0);
                    }
                }
        }
    }

    // epilogue: C/D layout col=lane&15, row=quad*4+reg
#pragma unroll
    for (int mi = 0; mi < 4; ++mi)
#pragma unroll
        for (int ni = 0; ni < NI; ++ni)
#pragma unroll
            for (int r = 0; r < 4; ++r) {
                const int m = m0 + wm * 64 + mi * 16 + quad * 4 + r;
                const int n = n0 + wn * (TN / 2) + ni * 16 + col;
                const float v = acc[mi][ni][r];
                if (OUT_MODE == 0) {
                    Cf[(size_t)m * DM + n] = v;
                } else {
                    const int b = m >> 11, s = m & (SS - 1);
                    const int tn = n >> 10;            // 0=Q, 1=K for fused QK
                    const int h = (n >> 6) & 15, d = n & 63;
                    const size_t idx = (size_t)tn * ((size_t)MM * DM) +
                                       ((size_t)((b << 4) + h) * SS + s) * HD + d;
                    if (OUT_MODE == 1) Cf[idx] = v;
                    else               Cb[idx] = f2bf(v);
                }
            }
}

// ---------------------------------------------------------------------------
// RoPE in-place on head-major fp32 Q and K. Folds 1/32 score scale into Q.
// ---------------------------------------------------------------------------
__global__ __launch_bounds__(256) void rope_f32(float* __restrict__ Qh, float* __restrict__ Kh)
{
    const int idx   = blockIdx.x * 256 + threadIdx.x;
    const int which = idx >> 21;
    const int rem   = idx & ((1 << 21) - 1);
    const int j     = rem & 31;
    const int bhs   = rem >> 5;
    const int s     = bhs & (SS - 1);

    float* p = (which ? Kh : Qh) + (size_t)bhs * HD;
    const float v1 = p[j];
    const float v2 = p[j + 32];
    const float inv_freq = powf(10000.f, -(float)j * (1.f / 32.f));
    const float f = (float)s * inv_freq;
    float sn, cs;
    sincosf(f, &sn, &cs);
    const float sc = which ? 1.f : (1.f / 32.f);
    p[j]      = (v1 * cs - v2 * sn) * sc;
    p[j + 32] = (v1 * sn + v2 * cs) * sc;
}

// ---------------------------------------------------------------------------
// MFMA flash attention (round-2 kernel; V now bf16 in, merged bf16 out).
// ---------------------------------------------------------------------------
#define PSTR 72

__global__ __launch_bounds__(256, 2) void attn_mfma(const float* __restrict__ Qh,
                                                    const float* __restrict__ Kh,
                                                    const ushort_t* __restrict__ Vh,
                                                    ushort_t* __restrict__ Mgb)
{
    __shared__ ushort_t KhiS[64 * PSTR];
    __shared__ ushort_t KloS[64 * PSTR];
    __shared__ ushort_t VtS [64 * PSTR];   // V transposed: [dim][key]
    __shared__ ushort_t PS  [128 * PSTR];  // P: [qrow-in-block][key]

    const int t    = threadIdx.x;
    const int w    = t >> 6;
    const int lane = t & 63;
    const int col  = lane & 15;
    const int quad = lane >> 4;

    const int bh = blockIdx.y;
    const int q0 = blockIdx.x * 128;
    const float*    Qb = Qh + (size_t)bh * SS * HD;
    const float*    Kb = Kh + (size_t)bh * SS * HD;
    const ushort_t* Vb = Vh + (size_t)bh * SS * HD;

    short8 qhi[2][2], qlo[2][2];
#pragma unroll
    for (int mi = 0; mi < 2; ++mi) {
#pragma unroll
        for (int ch = 0; ch < 2; ++ch) {
            const float* p = Qb + (size_t)(q0 + w * 32 + mi * 16 + col) * HD + ch * 32 + quad * 8;
            const float4 a = *(const float4*)p;
            const float4 b = *(const float4*)(p + 4);
            float v[8] = {a.x, a.y, a.z, a.w, b.x, b.y, b.z, b.w};
#pragma unroll
            for (int j = 0; j < 8; ++j) {
                const ushort_t h = f2bf(v[j]);
                qhi[mi][ch][j] = (short)h;
                qlo[mi][ch][j] = (short)f2bf(v[j] - bf2f(h));
            }
        }
    }

    floatx4 Oacc[2][4];
#pragma unroll
    for (int mi = 0; mi < 2; ++mi)
#pragma unroll
        for (int nt = 0; nt < 4; ++nt) Oacc[mi][nt] = (floatx4){0.f, 0.f, 0.f, 0.f};
    float mrow[2][4], lrow[2][4];
#pragma unroll
    for (int mi = 0; mi < 2; ++mi)
#pragma unroll
        for (int r = 0; r < 4; ++r) { mrow[mi][r] = -1e30f; lrow[mi][r] = 0.f; }

    const int skey = t >> 2;
    const int sd0  = (t & 3) * 16;

    for (int k0 = 0; k0 < SS; k0 += 64) {
        __syncthreads();
        {
            const float* kp = Kb + (size_t)(k0 + skey) * HD + sd0;
            float kv[16];
#pragma unroll
            for (int i = 0; i < 4; ++i)
                *(float4*)&kv[4 * i] = *(const float4*)(kp + 4 * i);
            short8 h0, h1, l0, l1;
#pragma unroll
            for (int i = 0; i < 16; ++i) {
                const ushort_t h = f2bf(kv[i]);
                const ushort_t l = f2bf(kv[i] - bf2f(h));
                if (i < 8) { h0[i] = (short)h; l0[i] = (short)l; }
                else       { h1[i - 8] = (short)h; l1[i - 8] = (short)l; }
            }
            *(short8*)&KhiS[skey * PSTR + sd0]     = h0;
            *(short8*)&KhiS[skey * PSTR + sd0 + 8] = h1;
            *(short8*)&KloS[skey * PSTR + sd0]     = l0;
            *(short8*)&KloS[skey * PSTR + sd0 + 8] = l1;

            const ushort_t* vp = Vb + (size_t)(k0 + skey) * HD + sd0;
            const short8 v0 = *(const short8*)vp;
            const short8 v1 = *(const short8*)(vp + 8);
#pragma unroll
            for (int i = 0; i < 8; ++i) {
                VtS[(sd0 + i)     * PSTR + skey] = (ushort_t)v0[i];
                VtS[(sd0 + 8 + i) * PSTR + skey] = (ushort_t)v1[i];
            }
        }
        __syncthreads();

        floatx4 sc[2][4];
#pragma unroll
        for (int nt = 0; nt < 4; ++nt) {
            short8 kh[2], kl[2];
#pragma unroll
            for (int ch = 0; ch < 2; ++ch) {
                kh[ch] = *(const short8*)&KhiS[(nt * 16 + col) * PSTR + ch * 32 + quad * 8];
                kl[ch] = *(const short8*)&KloS[(nt * 16 + col) * PSTR + ch * 32 + quad * 8];
            }
#pragma unroll
            for (int mi = 0; mi < 2; ++mi) {
                floatx4 a = (floatx4){0.f, 0.f, 0.f, 0.f};
#pragma unroll
                for (int ch = 0; ch < 2; ++ch)
                    a = __builtin_amdgcn_mfma_f32_16x16x32_bf16(qhi[mi][ch], kh[ch], a, 0, 0, 0);
#pragma unroll
                for (int ch = 0; ch < 2; ++ch)
                    a = __builtin_amdgcn_mfma_f32_16x16x32_bf16(qlo[mi][ch], kh[ch], a, 0, 0, 0);
#pragma unroll
                for (int ch = 0; ch < 2; ++ch)
                    a = __builtin_amdgcn_mfma_f32_16x16x32_bf16(qhi[mi][ch], kl[ch], a, 0, 0, 0);
                sc[mi][nt] = a;
            }
        }

#pragma unroll
        for (int mi = 0; mi < 2; ++mi) {
            float mx[4], al[4], ps[4];
#pragma unroll
            for (int r = 0; r < 4; ++r) {
                float m = sc[mi][0][r];
#pragma unroll
                for (int nt = 1; nt < 4; ++nt) m = fmaxf(m, sc[mi][nt][r]);
                m = fmaxf(m, __shfl_xor(m, 1));
                m = fmaxf(m, __shfl_xor(m, 2));
                m = fmaxf(m, __shfl_xor(m, 4));
                m = fmaxf(m, __shfl_xor(m, 8));
                mx[r] = m;
            }
#pragma unroll
            for (int r = 0; r < 4; ++r) {
                const float mnew = fmaxf(mrow[mi][r], mx[r]);
                al[r] = __expf(mrow[mi][r] - mnew);
                mrow[mi][r] = mnew;
                ps[r] = 0.f;
            }
#pragma unroll
            for (int nt = 0; nt < 4; ++nt)
#pragma unroll
                for (int r = 0; r < 4; ++r) {
                    const float p = __expf(sc[mi][nt][r] - mrow[mi][r]);
                    sc[mi][nt][r] = p;
                    ps[r] += p;
                }
#pragma unroll
            for (int r = 0; r < 4; ++r) {
                ps[r] += __shfl_xor(ps[r], 1);
                ps[r] += __shfl_xor(ps[r], 2);
                ps[r] += __shfl_xor(ps[r], 4);
                ps[r] += __shfl_xor(ps[r], 8);
                lrow[mi][r] = lrow[mi][r] * al[r] + ps[r];
            }
#pragma unroll
            for (int nt = 0; nt < 4; ++nt)
#pragma unroll
                for (int r = 0; r < 4; ++r) Oacc[mi][nt][r] *= al[r];
#pragma unroll
            for (int nt = 0; nt < 4; ++nt)
#pragma unroll
                for (int r = 0; r < 4; ++r)
                    PS[(w * 32 + mi * 16 + quad * 4 + r) * PSTR + nt * 16 + col] =
                        f2bf(sc[mi][nt][r]);
        }

#pragma unroll
        for (int nt = 0; nt < 4; ++nt) {
            short8 vf[2];
#pragma unroll
            for (int ch = 0; ch < 2; ++ch)
                vf[ch] = *(const short8*)&VtS[(nt * 16 + col) * PSTR + ch * 32 + quad * 8];
#pragma unroll
            for (int mi = 0; mi < 2; ++mi) {
                short8 pf[2];
#pragma unroll
                for (int ch = 0; ch < 2; ++ch)
                    pf[ch] = *(const short8*)&PS[(w * 32 + mi * 16 + col) * PSTR + ch * 32 + quad * 8];
#pragma unroll
                for (int ch = 0; ch < 2; ++ch)
                    Oacc[mi][nt] = __builtin_amdgcn_mfma_f32_16x16x32_bf16(pf[ch], vf[ch], Oacc[mi][nt], 0, 0, 0);
            }
        }
    }

    const int b = bh >> 4, h = bh & 15;
#pragma unroll
    for (int mi = 0; mi < 2; ++mi) {
        float inv[4];
#pragma unroll
        for (int r = 0; r < 4; ++r) inv[r] = 1.f / lrow[mi][r];
#pragma unroll
        for (int nt = 0; nt < 4; ++nt)
#pragma unroll
            for (int r = 0; r < 4; ++r) {
                const int srow = q0 + w * 32 + mi * 16 + quad * 4 + r;
                Mgb[(size_t)(b * SS + srow) * DM + h * HD + nt * 16 + col] =
                    f2bf(Oacc[mi][nt][r] * inv[r]);
            }
    }
}

// ---------------------------------------------------------------------------
extern "C" void kernel_launch(void* const* d_in, const int* in_sizes, int n_in,
                              void* d_out, int out_size, void* d_ws, size_t ws_size,
                              hipStream_t stream)
{
    const float* x  = (const float*)d_in[0];
    const float* qw = (const float*)d_in[1];
    const float* kw = (const float*)d_in[2];
    const float* vw = (const float*)d_in[3];
    const float* ow = (const float*)d_in[4];
    float* out = (float*)d_out;

    // ws layout (76 MB):
    float*    Qh  = (float*)d_ws;                      // 16 MB fp32 head-major
    float*    Kh  = Qh + (size_t)MM * DM;              // 16 MB
    ushort_t* Vhb = (ushort_t*)(Kh + (size_t)MM * DM); // 8 MB bf16 head-major
    ushort_t* Mgb = Vhb + (size_t)MM * DM;             // 8 MB bf16 merged
    ushort_t* xh  = Mgb + (size_t)MM * DM;             // 8 MB
    ushort_t* xl  = xh  + (size_t)MM * DM;             // 8 MB
    ushort_t* qkh = xl  + (size_t)MM * DM;             // 4 MB  [2048][1024]
    ushort_t* qkl = qkh + (size_t)2048 * DM;           // 4 MB
    ushort_t* vwt = qkl + (size_t)2048 * DM;           // 2 MB  [1024][1024]
    ushort_t* owt = vwt + (size_t)DM * DM;             // 2 MB

    convert_x<<<(MM * DM) / (256 * 8), 256, 0, stream>>>(x, xh, xl);
    convert_wt<1><<<dim3(16, 16), 256, 0, stream>>>(qw, qkh, qkl);
    convert_wt<1><<<dim3(16, 16), 256, 0, stream>>>(kw, qkh + (size_t)DM * DM, qkl + (size_t)DM * DM);
    convert_wt<0><<<dim3(16, 16), 256, 0, stream>>>(vw, vwt, nullptr);
    convert_wt<0><<<dim3(16, 16), 256, 0, stream>>>(ow, owt, nullptr);

    // fused Q|K projection: split-bf16, head-major fp32 out (Qh then Kh)
    gemm_mfma<1, 1, 128, 32><<<dim3(2048 / 128, MM / GTM), 256, 0, stream>>>(
        xh, xl, qkh, qkl, Qh, nullptr);
    // V projection: plain bf16, head-major bf16 out
    gemm_mfma<0, 2, 64, 64><<<dim3(DM / 64, MM / GTM), 256, 0, stream>>>(
        xh, nullptr, vwt, nullptr, nullptr, Vhb);

    rope_f32<<<(2 * BB * NH * SS * 32) / 256, 256, 0, stream>>>(Qh, Kh);

    attn_mfma<<<dim3(SS / 128, BB * NH), 256, 0, stream>>>(Qh, Kh, Vhb, Mgb);

    // out projection: plain bf16, flat fp32 out
    gemm_mfma<0, 0, 64, 64><<<dim3(DM / 64, MM / GTM), 256, 0, stream>>>(
        Mgb, nullptr, owt, nullptr, out, nullptr);
}

// Round 4
// 271.518 us; speedup vs baseline: 6.0188x; 1.2493x over previous
//
#include <hip/hip_runtime.h>
#include <math.h>

#define DM 1024   // d_model
#define NH 16     // heads
#define HD 64     // head dim
#define BB 2      // batch
#define SS 2048   // seq
#define MM (BB*SS)

typedef unsigned short ushort_t;
typedef __attribute__((ext_vector_type(8))) short short8;    // 8 bf16 = MFMA A/B fragment
typedef __attribute__((ext_vector_type(4))) short short4_t;  // 4 bf16 (8B)
typedef __attribute__((ext_vector_type(4))) float floatx4;   // MFMA C/D fragment

// bf16 helpers (RNE)
__device__ __forceinline__ ushort_t f2bf(float f) {
    unsigned int u = __float_as_uint(f);
    unsigned int r = u + 0x7fffu + ((u >> 16) & 1u);
    return (ushort_t)(r >> 16);
}
__device__ __forceinline__ float bf2f(ushort_t h) {
    return __uint_as_float(((unsigned int)h) << 16);
}

// async 16B global->LDS (per-lane global addr, wave-uniform LDS base + lane*16)
__device__ __forceinline__ void gl_lds16(const ushort_t* g, ushort_t* l) {
    __builtin_amdgcn_global_load_lds(
        (const __attribute__((address_space(1))) unsigned int*)g,
        (__attribute__((address_space(3))) unsigned int*)l, 16, 0, 0);
}

// ---------------------------------------------------------------------------
// RoPE cos/sin table: ct[s*32+j] = (cos(s*invf(j)), sin(s*invf(j)))
// ---------------------------------------------------------------------------
__global__ __launch_bounds__(256) void freq_kernel(float2* __restrict__ ct)
{
    const int idx = blockIdx.x * 256 + threadIdx.x;   // SS*32
    const int s = idx >> 5, j = idx & 31;
    const float invf = powf(10000.f, -(float)j * (1.f / 32.f));
    float sn, cs;
    sincosf((float)s * invf, &sn, &cs);
    ct[idx] = make_float2(cs, sn);
}

// ---------------------------------------------------------------------------
// Conversions
// ---------------------------------------------------------------------------
__global__ __launch_bounds__(256) void convert_x(const float* __restrict__ X,
                                                 ushort_t* __restrict__ Xh,
                                                 ushort_t* __restrict__ Xl)
{
    const size_t base = ((size_t)blockIdx.x * 256 + threadIdx.x) * 8;
    float v[8];
    *(float4*)&v[0] = *(const float4*)(X + base);
    *(float4*)&v[4] = *(const float4*)(X + base + 4);
    short8 h, l;
#pragma unroll
    for (int i = 0; i < 8; ++i) {
        const ushort_t hi = f2bf(v[i]);
        h[i] = (short)hi;
        l[i] = (short)f2bf(v[i] - bf2f(hi));
    }
    *(short8*)(Xh + base) = h;
    *(short8*)(Xl + base) = l;
}

// W[k][n] fp32 -> Wt[n][k] bf16 hi (+lo). grid (nb, kb), 64x64 tiles.
template<int SPLIT>
__global__ __launch_bounds__(256) void convert_wt(const float* __restrict__ W,
                                                  ushort_t* __restrict__ Th,
                                                  ushort_t* __restrict__ Tl)
{
    __shared__ float tile[64][65];
    const int t  = threadIdx.x;
    const int kb = blockIdx.y * 64, nb = blockIdx.x * 64;
    const int r  = t >> 2;
    const int c0 = (t & 3) * 16;
#pragma unroll
    for (int i = 0; i < 4; ++i)
        *(float4*)&tile[r][c0 + 4 * i] = *(const float4*)(W + (size_t)(kb + r) * DM + nb + c0 + 4 * i);
    __syncthreads();
    ushort_t hi[16], lo[16];
#pragma unroll
    for (int i = 0; i < 16; ++i) {
        const float v = tile[c0 + i][r];
        hi[i] = f2bf(v);
        if (SPLIT) lo[i] = f2bf(v - bf2f(hi[i]));
    }
    const size_t dst = (size_t)(nb + r) * DM + kb + c0;
    *(short8*)(Th + dst)     = *(short8*)&hi[0];
    *(short8*)(Th + dst + 8) = *(short8*)&hi[8];
    if (SPLIT) {
        *(short8*)(Tl + dst)     = *(short8*)&lo[0];
        *(short8*)(Tl + dst + 8) = *(short8*)&lo[8];
    }
}

// ---------------------------------------------------------------------------
// MFMA GEMM. C[M x N] = A[M x K] @ Bt[N x K]^T, bf16 (optional hi+lo 3-term),
// fp32 acc. Tile 128 x TN, BK k-step, 4 waves 2x2.
// OUT_MODE: 0 flat fp32 | 2 V: bf16 transposed head-major [b,h,d,s] via LDS
//           | 3 fused QK+RoPE: Q fp32 head-major (x1/32), K bf16 hi/lo head-major
// ---------------------------------------------------------------------------
#define GTM 128

template<int UPR, int SH>
__device__ __forceinline__ void stage_tile(const ushort_t* __restrict__ G,
                                           ushort_t* L, int rows, int w, int lane)
{
    const int iters = rows * UPR / 256;
#pragma unroll
    for (int i = 0; i < iters; ++i) {
        const int p0 = (i * 4 + w) * 64;
        const int p  = p0 + lane;
        const int r  = p / UPR;
        const int u  = (p % UPR) ^ ((r >> SH) & (UPR - 1));
        gl_lds16(G + (size_t)r * DM + u * 8, L + (size_t)p0 * 8);
    }
}

template<int UPR, int SH>
__device__ __forceinline__ short8 frag(const ushort_t* L, int r, int u)
{
    const int uu = u ^ ((r >> SH) & (UPR - 1));
    return *(const short8*)&L[((size_t)r * UPR + uu) * 8];
}

template<int SPLIT, int OUT_MODE, int TN, int BK>
__global__ __launch_bounds__(256, 2) void gemm_mfma(
    const ushort_t* __restrict__ Ah, const ushort_t* __restrict__ Al,
    const ushort_t* __restrict__ Bh, const ushort_t* __restrict__ Bl,
    float* __restrict__ Cf, ushort_t* __restrict__ Cb, ushort_t* __restrict__ Cb2,
    const float2* __restrict__ CT)
{
    constexpr int UPR = BK / 8;
    constexpr int KC  = BK / 32;
    constexpr int NI  = TN / 32;
    constexpr int SH  = (UPR == 4) ? 1 : 0;

    __shared__ __align__(16) ushort_t AsH[GTM * BK];
    __shared__ __align__(16) ushort_t BsH[TN * BK];
    __shared__ __align__(16) ushort_t AsL[SPLIT ? GTM * BK : 8];
    __shared__ __align__(16) ushort_t BsL[SPLIT ? TN * BK : 8];
    __shared__ __align__(16) ushort_t Ts[(OUT_MODE == 2) ? 64 * 136 : 8];

    const int t    = threadIdx.x;
    const int w    = t >> 6;
    const int lane = t & 63;
    const int col  = lane & 15;
    const int quad = lane >> 4;
    const int wm   = w & 1;
    const int wn   = w >> 1;
    const int m0   = blockIdx.y * GTM;
    const int n0   = blockIdx.x * TN;

    floatx4 acc[4][NI];
#pragma unroll
    for (int mi = 0; mi < 4; ++mi)
#pragma unroll
        for (int ni = 0; ni < NI; ++ni) acc[mi][ni] = (floatx4){0.f, 0.f, 0.f, 0.f};

    for (int k0 = 0; k0 < DM; k0 += BK) {
        __syncthreads();
        stage_tile<UPR, SH>(Ah + (size_t)m0 * DM + k0, AsH, GTM, w, lane);
        if (SPLIT) stage_tile<UPR, SH>(Al + (size_t)m0 * DM + k0, AsL, GTM, w, lane);
        stage_tile<UPR, SH>(Bh + (size_t)n0 * DM + k0, BsH, TN, w, lane);
        if (SPLIT) stage_tile<UPR, SH>(Bl + (size_t)n0 * DM + k0, BsL, TN, w, lane);
        __syncthreads();

#pragma unroll
        for (int kc = 0; kc < KC; ++kc) {
            short8 ah[4], bh[NI];
            short8 al[SPLIT ? 4 : 1], bl[SPLIT ? NI : 1];
#pragma unroll
            for (int mi = 0; mi < 4; ++mi) {
                const int r = wm * 64 + mi * 16 + col;
                ah[mi] = frag<UPR, SH>(AsH, r, kc * 4 + quad);
                if (SPLIT) al[mi] = frag<UPR, SH>(AsL, r, kc * 4 + quad);
            }
#pragma unroll
            for (int ni = 0; ni < NI; ++ni) {
                const int r = wn * (TN / 2) + ni * 16 + col;
                bh[ni] = frag<UPR, SH>(BsH, r, kc * 4 + quad);
                if (SPLIT) bl[ni] = frag<UPR, SH>(BsL, r, kc * 4 + quad);
            }
#pragma unroll
            for (int mi = 0; mi < 4; ++mi)
#pragma unroll
                for (int ni = 0; ni < NI; ++ni) {
                    acc[mi][ni] = __builtin_amdgcn_mfma_f32_16x16x32_bf16(ah[mi], bh[ni], acc[mi][ni], 0, 0, 0);
                    if (SPLIT) {
                        acc[mi][ni] = __builtin_amdgcn_mfma_f32_16x16x32_bf16(al[mi], bh[ni], acc[mi][ni], 0, 0, 0);
                        acc[mi][ni] = __builtin_amdgcn_mfma_f32_16x16x32_bf16(ah[mi], bl[ni], acc[mi][ni], 0, 0, 0);
                    }
                }
        }
    }

    // ---- epilogues (C/D layout: col=lane&15, row=quad*4+reg) ----
    if constexpr (OUT_MODE == 0) {
#pragma unroll
        for (int mi = 0; mi < 4; ++mi)
#pragma unroll
            for (int ni = 0; ni < NI; ++ni)
#pragma unroll
                for (int r = 0; r < 4; ++r) {
                    const int m = m0 + wm * 64 + mi * 16 + quad * 4 + r;
                    const int n = n0 + wn * (TN / 2) + ni * 16 + col;
                    Cf[(size_t)m * DM + n] = acc[mi][ni][r];
                }
    }
    if constexpr (OUT_MODE == 2) {
        // transpose in LDS -> Vt[b, h, d, s] bf16, coalesced b128 stores
#pragma unroll
        for (int mi = 0; mi < 4; ++mi)
#pragma unroll
            for (int ni = 0; ni < NI; ++ni) {
                const int nl = wn * (TN / 2) + ni * 16 + col;      // d 0..63
                const int ml = wm * 64 + mi * 16 + quad * 4;       // s-local
                short4_t pk;
#pragma unroll
                for (int r = 0; r < 4; ++r) pk[r] = (short)f2bf(acc[mi][ni][r]);
                *(short4_t*)&Ts[nl * 136 + ml] = pk;
            }
        __syncthreads();
        const int b = m0 >> 11, h = n0 >> 6;
        const int s0 = m0 & (SS - 1);
#pragma unroll
        for (int it = 0; it < 4; ++it) {
            const int idx = it * 256 + t;
            const int dr = idx >> 4, u = idx & 15;
            const short8 v = *(const short8*)&Ts[dr * 136 + u * 8];
            *(short8*)(Cb + ((size_t)((b << 4) + h) * HD + dr) * SS + s0 + u * 8) = v;
        }
    }
    if constexpr (OUT_MODE == 3) {
        // fused RoPE; tn: 0=Q (fp32, x1/32), 1=K (bf16 hi/lo). Block-uniform.
        const int tn = n0 >> 10;
#pragma unroll
        for (int mi = 0; mi < 4; ++mi)
#pragma unroll
            for (int ni = 0; ni < 2; ++ni)
#pragma unroll
                for (int r = 0; r < 4; ++r) {
                    const int m = m0 + wm * 64 + mi * 16 + quad * 4 + r;
                    const int n = n0 + wn * (TN / 2) + ni * 16 + col;
                    const int b = m >> 11, s = m & (SS - 1);
                    const int h = (n >> 6) & 15, d = n & 63;       // d in 0..31
                    const float2 cs = CT[(s << 5) + d];
                    const float x1 = acc[mi][ni][r];
                    const float x2 = acc[mi][ni + 2][r];
                    const float y1 = x1 * cs.x - x2 * cs.y;
                    const float y2 = x1 * cs.y + x2 * cs.x;
                    const size_t base = ((size_t)((b << 4) + h) * SS + s) * HD + d;
                    if (tn == 0) {
                        Cf[base]      = y1 * (1.f / 32.f);
                        Cf[base + 32] = y2 * (1.f / 32.f);
                    } else {
                        const ushort_t h1 = f2bf(y1), h2 = f2bf(y2);
                        Cb [base]      = h1;
                        Cb [base + 32] = h2;
                        Cb2[base]      = f2bf(y1 - bf2f(h1));
                        Cb2[base + 32] = f2bf(y2 - bf2f(h2));
                    }
                }
    }
}

// ---------------------------------------------------------------------------
// MFMA flash attention, S^T formulation.
// S^T = K.Q^T (operand-swapped MFMA): C-layout col=qrow, row(reg)=key -> P
// writes are packed b64 along keys; softmax cross-lane = xor16/xor32 only.
// K pre-split (hi/lo bf16), V pre-transposed: staging = pure global_load_lds
// with XOR swizzle on 16B units (conflict-free stage AND frag reads).
// ---------------------------------------------------------------------------
__device__ __forceinline__ short8 afrag(const ushort_t* S, int r, int lu)
{
    return *(const short8*)&S[(size_t)(((r << 3) | (lu ^ (r & 7))) << 3)];
}

__global__ __launch_bounds__(256, 2) void attn_mfma2(
    const float* __restrict__ Qh, const ushort_t* __restrict__ Khi,
    const ushort_t* __restrict__ Klo, const ushort_t* __restrict__ Vt,
    ushort_t* __restrict__ Mgb)
{
    __shared__ __align__(16) ushort_t KhiS[64 * 64];   // [key][dim] 8KB
    __shared__ __align__(16) ushort_t KloS[64 * 64];
    __shared__ __align__(16) ushort_t VtS [64 * 64];   // [dim][key]
    __shared__ __align__(16) ushort_t PS  [128 * 64];  // [qrow][key] 16KB

    const int t    = threadIdx.x;
    const int w    = t >> 6;
    const int lane = t & 63;
    const int col  = lane & 15;
    const int quad = lane >> 4;

    const int bh = blockIdx.y;
    const int q0 = blockIdx.x * 128;
    const float*    Qb  = Qh  + (size_t)bh * SS * HD;
    const ushort_t* KhB = Khi + (size_t)bh * SS * HD;
    const ushort_t* KlB = Klo + (size_t)bh * SS * HD;
    const ushort_t* VtB = Vt  + (size_t)bh * HD * SS;

    // Q fragments (rows = this wave's 32 qrows), split hi/lo once
    short8 qhi[2][2], qlo[2][2];
#pragma unroll
    for (int mi = 0; mi < 2; ++mi) {
#pragma unroll
        for (int ch = 0; ch < 2; ++ch) {
            const float* p = Qb + (size_t)(q0 + w * 32 + mi * 16 + col) * HD + ch * 32 + quad * 8;
            const float4 a = *(const float4*)p;
            const float4 b = *(const float4*)(p + 4);
            float v[8] = {a.x, a.y, a.z, a.w, b.x, b.y, b.z, b.w};
#pragma unroll
            for (int j = 0; j < 8; ++j) {
                const ushort_t h = f2bf(v[j]);
                qhi[mi][ch][j] = (short)h;
                qlo[mi][ch][j] = (short)f2bf(v[j] - bf2f(h));
            }
        }
    }

    floatx4 Oacc[2][4];
#pragma unroll
    for (int mi = 0; mi < 2; ++mi)
#pragma unroll
        for (int nt = 0; nt < 4; ++nt) Oacc[mi][nt] = (floatx4){0.f, 0.f, 0.f, 0.f};
    float mstat[2] = {-1e30f, -1e30f}, lstat[2] = {0.f, 0.f};

    for (int k0 = 0; k0 < SS; k0 += 64) {
        __syncthreads();
        // stage K hi/lo + V^T: pure async DMA, swizzled placement
#pragma unroll
        for (int i = 0; i < 2; ++i) {
            const int p0 = w * 128 + i * 64;
            const int p  = p0 + lane;
            const int r  = p >> 3;
            const int gu = (p & 7) ^ (r & 7);
            gl_lds16(KhB + (size_t)(k0 + r) * HD + gu * 8, KhiS + (size_t)p0 * 8);
            gl_lds16(KlB + (size_t)(k0 + r) * HD + gu * 8, KloS + (size_t)p0 * 8);
            gl_lds16(VtB + (size_t)r * SS + k0 + gu * 8,   VtS  + (size_t)p0 * 8);
        }
        __syncthreads();

        // S^T = Khi.Qhi^T + Khi.Qlo^T + Klo.Qhi^T
        floatx4 sc[4][2];
#pragma unroll
        for (int kt = 0; kt < 4; ++kt) {
            short8 kh[2], kl[2];
#pragma unroll
            for (int ch = 0; ch < 2; ++ch) {
                kh[ch] = afrag(KhiS, kt * 16 + col, ch * 4 + quad);
                kl[ch] = afrag(KloS, kt * 16 + col, ch * 4 + quad);
            }
#pragma unroll
            for (int mi = 0; mi < 2; ++mi) {
                floatx4 a = (floatx4){0.f, 0.f, 0.f, 0.f};
#pragma unroll
                for (int ch = 0; ch < 2; ++ch)
                    a = __builtin_amdgcn_mfma_f32_16x16x32_bf16(kh[ch], qhi[mi][ch], a, 0, 0, 0);
#pragma unroll
                for (int ch = 0; ch < 2; ++ch)
                    a = __builtin_amdgcn_mfma_f32_16x16x32_bf16(kh[ch], qlo[mi][ch], a, 0, 0, 0);
#pragma unroll
                for (int ch = 0; ch < 2; ++ch)
                    a = __builtin_amdgcn_mfma_f32_16x16x32_bf16(kl[ch], qhi[mi][ch], a, 0, 0, 0);
                sc[kt][mi] = a;
            }
        }

        // online softmax: lane owns qrow=col; keys = kt*16 + quad*4 + r
#pragma unroll
        for (int mi = 0; mi < 2; ++mi) {
            float mloc = -1e30f;
#pragma unroll
            for (int kt = 0; kt < 4; ++kt)
#pragma unroll
                for (int r = 0; r < 4; ++r) mloc = fmaxf(mloc, sc[kt][mi][r]);
            mloc = fmaxf(mloc, __shfl_xor(mloc, 16));
            mloc = fmaxf(mloc, __shfl_xor(mloc, 32));
            const float mnew  = fmaxf(mstat[mi], mloc);
            const float alpha = __expf(mstat[mi] - mnew);
            mstat[mi] = mnew;

            float psum = 0.f;
            const int qrow = w * 32 + mi * 16 + col;
#pragma unroll
            for (int kt = 0; kt < 4; ++kt) {
                short4_t pk;
#pragma unroll
                for (int r = 0; r < 4; ++r) {
                    const float p = __expf(sc[kt][mi][r] - mnew);
                    psum += p;
                    pk[r] = (short)f2bf(p);
                }
                const int u = (kt * 2 + (quad >> 1)) ^ (col & 7);
                *(short4_t*)&PS[(qrow << 6) + (u << 3) + ((quad & 1) << 2)] = pk;
            }
            psum += __shfl_xor(psum, 16);
            psum += __shfl_xor(psum, 32);
            lstat[mi] = lstat[mi] * alpha + psum;

            // alpha to row-space (O rows = quad*4+r) and rescale O
            floatx4 alr;
#pragma unroll
            for (int r = 0; r < 4; ++r) alr[r] = __shfl(alpha, quad * 4 + r, 64);
#pragma unroll
            for (int nt = 0; nt < 4; ++nt)
#pragma unroll
                for (int r = 0; r < 4; ++r) Oacc[mi][nt][r] *= alr[r];
        }

        // PV: O[qrow][dim] += P[qrow][key] . V^T[dim][key]^T  (wave-local PS)
        short8 pf[2][2];
#pragma unroll
        for (int mi = 0; mi < 2; ++mi)
#pragma unroll
            for (int ch = 0; ch < 2; ++ch)
                pf[mi][ch] = afrag(PS, w * 32 + mi * 16 + col, ch * 4 + quad);
#pragma unroll
        for (int nt = 0; nt < 4; ++nt) {
            short8 vf[2];
#pragma unroll
            for (int ch = 0; ch < 2; ++ch)
                vf[ch] = afrag(VtS, nt * 16 + col, ch * 4 + quad);
#pragma unroll
            for (int mi = 0; mi < 2; ++mi)
#pragma unroll
                for (int ch = 0; ch < 2; ++ch)
                    Oacc[mi][nt] = __builtin_amdgcn_mfma_f32_16x16x32_bf16(pf[mi][ch], vf[ch], Oacc[mi][nt], 0, 0, 0);
        }
    }

    // epilogue: merged[b, s, h*64+d] bf16
    const int b = bh >> 4, h = bh & 15;
#pragma unroll
    for (int mi = 0; mi < 2; ++mi) {
        floatx4 linv;
#pragma unroll
        for (int r = 0; r < 4; ++r) linv[r] = 1.f / __shfl(lstat[mi], quad * 4 + r, 64);
#pragma unroll
        for (int nt = 0; nt < 4; ++nt)
#pragma unroll
            for (int r = 0; r < 4; ++r) {
                const int srow = q0 + w * 32 + mi * 16 + quad * 4 + r;
                Mgb[(size_t)(b * SS + srow) * DM + h * HD + nt * 16 + col] =
                    f2bf(Oacc[mi][nt][r] * linv[r]);
            }
    }
}

// ---------------------------------------------------------------------------
extern "C" void kernel_launch(void* const* d_in, const int* in_sizes, int n_in,
                              void* d_out, int out_size, void* d_ws, size_t ws_size,
                              hipStream_t stream)
{
    const float* x  = (const float*)d_in[0];
    const float* qw = (const float*)d_in[1];
    const float* kw = (const float*)d_in[2];
    const float* vw = (const float*)d_in[3];
    const float* ow = (const float*)d_in[4];
    float* out = (float*)d_out;

    // ws layout (~76.5 MB)
    float*    Qh  = (float*)d_ws;                       // 16 MB fp32 head-major (rope'd, /32)
    ushort_t* Khi = (ushort_t*)(Qh + (size_t)MM * DM);  // 8 MB bf16 head-major (rope'd)
    ushort_t* Klo = Khi + (size_t)MM * DM;              // 8 MB
    ushort_t* Vtb = Klo + (size_t)MM * DM;              // 8 MB bf16 [b,h,d,s]
    ushort_t* Mgb = Vtb + (size_t)MM * DM;              // 8 MB bf16 merged
    ushort_t* xh  = Mgb + (size_t)MM * DM;              // 8 MB
    ushort_t* xl  = xh  + (size_t)MM * DM;              // 8 MB
    ushort_t* qkh = xl  + (size_t)MM * DM;              // 4 MB [2048][1024]
    ushort_t* qkl = qkh + (size_t)2048 * DM;            // 4 MB
    ushort_t* vwt = qkl + (size_t)2048 * DM;            // 2 MB
    ushort_t* owt = vwt + (size_t)DM * DM;              // 2 MB
    float2*   ct  = (float2*)(owt + (size_t)DM * DM);   // 0.5 MB

    freq_kernel<<<(SS * 32) / 256, 256, 0, stream>>>(ct);
    convert_x<<<(MM * DM) / (256 * 8), 256, 0, stream>>>(x, xh, xl);
    convert_wt<1><<<dim3(16, 16), 256, 0, stream>>>(qw, qkh, qkl);
    convert_wt<1><<<dim3(16, 16), 256, 0, stream>>>(kw, qkh + (size_t)DM * DM, qkl + (size_t)DM * DM);
    convert_wt<0><<<dim3(16, 16), 256, 0, stream>>>(vw, vwt, nullptr);
    convert_wt<0><<<dim3(16, 16), 256, 0, stream>>>(ow, owt, nullptr);

    // fused Q|K projection + RoPE: split-bf16 3-term
    gemm_mfma<1, 3, 128, 32><<<dim3(2048 / 128, MM / GTM), 256, 0, stream>>>(
        xh, xl, qkh, qkl, Qh, Khi, Klo, ct);
    // V projection -> transposed bf16 [b,h,d,s]
    gemm_mfma<0, 2, 64, 64><<<dim3(DM / 64, MM / GTM), 256, 0, stream>>>(
        xh, nullptr, vwt, nullptr, nullptr, Vtb, nullptr, nullptr);

    attn_mfma2<<<dim3(SS / 128, BB * NH), 256, 0, stream>>>(Qh, Khi, Klo, Vtb, Mgb);

    // out projection
    gemm_mfma<0, 0, 64, 64><<<dim3(DM / 64, MM / GTM), 256, 0, stream>>>(
        Mgb, nullptr, owt, nullptr, out, nullptr, nullptr, nullptr);
}